// Round 6
// baseline (979.838 us; speedup 1.0000x reference)
//
#include <hip/hip_runtime.h>

#define NT 128      // num tags
#define SEQ 1024    // sequence length
#define NB 256      // batch

// One DPP max step on the VALU pipe (no DS/lgkmcnt involvement).
#define DPP_MAX_STEP(x, ctrl)                                                   \
    fmaxf((x), __builtin_bit_cast(float, __builtin_amdgcn_update_dpp(           \
        __builtin_bit_cast(int, (x)), __builtin_bit_cast(int, (x)),             \
        (ctrl), 0xf, 0xf, false)))

__device__ __forceinline__ float wave_max_dpp(float x) {
    x = DPP_MAX_STEP(x, 0x111);   // row_shr:1
    x = DPP_MAX_STEP(x, 0x112);   // row_shr:2
    x = DPP_MAX_STEP(x, 0x114);   // row_shr:4
    x = DPP_MAX_STEP(x, 0x118);   // row_shr:8
    x = DPP_MAX_STEP(x, 0x142);   // row_bcast:15
    x = DPP_MAX_STEP(x, 0x143);   // row_bcast:31
    return __builtin_bit_cast(float, __builtin_amdgcn_readlane(
        __builtin_bit_cast(int, x), 63));
}

// Dual f32 FMA (VOP3P). 2 MACs per instruction at full VALU rate -- 2x the
// MAC rate of v_dot2_f32_f16, in full f32 precision.
__device__ __forceinline__ float2 pk_fma(float2 a, float2 b, float2 c) {
    float2 d;
    asm("v_pk_fma_f32 %0, %1, %2, %3" : "=v"(d) : "v"(a), "v"(b), "v"(c));
    return d;
}

// One scan step, 2-wave cooperative version. Lane owns ONE column c = tid;
// the full 128-long dot is lane-local (no cross-lane combines, no f16 pack).
// P (f32, 128 floats) is double-buffered in LDS; one __syncthreads per step
// (ping-pong: reads of BUF precede the barrier, writes of BUF^1 follow the
// previous one). The 2 per-wave maxes ride the same barrier.
#define CRF_STEP(RC, RN, MC, DO_PRE, K, BUF)                                     \
    {                                                                            \
        float mcur = MC;                                                         \
        if (DO_PRE) { RC = emp[(K) * NT]; MC = mpp[K]; }                         \
        float eRN = __expf(RN);          /* for NEXT step's ex; off chain */     \
        const float4* p4r = (const float4*)&p_s[BUF][0];                         \
        float2 a0{0.f,0.f}, a1{0.f,0.f}, a2{0.f,0.f}, a3{0.f,0.f};               \
        _Pragma("unroll")                                                        \
        for (int q = 0; q < 16; ++q) {                                           \
            float4 Pa = p4r[2*q];                                                \
            float4 Pb = p4r[2*q+1];                                              \
            a0 = pk_fma(float2{Pa.x, Pa.y}, Ep[4*q+0], a0);                      \
            a1 = pk_fma(float2{Pa.z, Pa.w}, Ep[4*q+1], a1);                      \
            a2 = pk_fma(float2{Pb.x, Pb.y}, Ep[4*q+2], a2);                      \
            a3 = pk_fma(float2{Pb.z, Pb.w}, Ep[4*q+3], a3);                      \
        }                                                                        \
        float sv = ((a0.x + a0.y) + (a1.x + a1.y))                               \
                 + ((a2.x + a2.y) + (a3.x + a3.y));                              \
        float v = sv * ex;                                                       \
        if (mcur > 0.0f) { cur = v; offset += offadd; }                          \
        p_s[(BUF)^1][c] = cur;           /* raw f32, 1 ds_write_b32 */           \
        float wm = wave_max_dpp(cur);                                            \
        if (l == 0) wmax[(BUF)^1][w] = wm;                                       \
        __syncthreads();                                                         \
        float2 wv = *(const float2*)&wmax[(BUF)^1][0];                           \
        mx = fmaxf(wv.x, wv.y);                                                  \
        inv = __builtin_amdgcn_rcpf(mx);                                         \
        offadd = __logf(mx);                                                     \
        ex = eRN * inv;                                                          \
    }

// TWO WAVES per batch element. 256 blocks x 128 threads. R4->R5 showed
// per-wave overhead (~290 cy) is fixed regardless of work split and barrier
// cost grows with wave count -- so use the FEWEST waves that still split the
// matvec: per-wave issue = 64 pk_fma (128 MACs) + overhead, with a narrow
// 2-wave barrier and a lean f32 exchange. E (prob domain) is f32 in 128
// VGPRs (no f16 quantization anywhere).
__global__ __launch_bounds__(128, 1) void crf_scan_kernel(
    const float* __restrict__ emissions,    // [B,S,T]
    const float* __restrict__ masks,        // [B,S]
    const int*   __restrict__ tags,         // [B,S]
    const float* __restrict__ transitions,  // [T,T] (log domain)
    const float* __restrict__ start_t,      // [T]
    const float* __restrict__ end_t,        // [T]
    float* __restrict__ out_per_batch)      // [B]
{
    const int b   = blockIdx.x;
    const int tid = threadIdx.x;
    const int w   = tid >> 6;     // wave 0..1
    const int l   = tid & 63;     // lane 0..63
    const int c   = tid;          // owned output column 0..127

    __shared__ __align__(16) float p_s[2][NT];   // f32 P, double-buffered
    __shared__ __align__(16) float wmax[2][2];   // per-wave maxes
    __shared__ float redA[2], redB[2], redC[2];  // epilogue reductions
    __shared__ float msk_s[SEQ];

    // ---- E column c in registers, f32 pairs along the row (i) dim ----
    float2 Ep[64];
    #pragma unroll
    for (int r = 0; r < 64; ++r) {
        float ea = transitions[(2*r    ) * NT + c];
        float ob = transitions[(2*r + 1) * NT + c];
        Ep[r] = float2{__expf(ea), __expf(ob)};
    }

    for (int s = tid; s < SEQ; s += 128)
        msk_s[s] = masks[b * SEQ + s];

    // ---- init: P = exp(start), offset = 0 ----
    float cur = __expf(start_t[c]);
    float offset = 0.0f;

    p_s[0][c] = cur;
    {
        float wm = wave_max_dpp(cur);
        if (l == 0) wmax[0][w] = wm;
    }
    __syncthreads();

    float2 wv0 = *(const float2*)&wmax[0][0];
    float mx   = fmaxf(wv0.x, wv0.y);
    float inv  = __builtin_amdgcn_rcpf(mx);
    float offadd = __logf(mx);

    const float* eb  = emissions + (size_t)b * SEQ * NT;
    const float* mkp = masks + b * SEQ;

    // depth-4 rings: slot k holds em/mask for step s with s&3==k (scalar)
    float ring0 = eb[(size_t)0 * NT + c];
    float ring1 = eb[(size_t)1 * NT + c];
    float ring2 = eb[(size_t)2 * NT + c];
    float ring3 = eb[(size_t)3 * NT + c];
    float mr0 = mkp[0], mr1 = mkp[1], mr2 = mkp[2], mr3 = mkp[3];

    float ex = __expf(ring0) * inv;

    const float* emp = eb + 4 * NT + c;   // em[s+4] for s=0
    const float* mpp = mkp + 4;

    // main loop: steps 0..1019, unrolled x4 (ring slots static; BUF = s&1)
    for (int it = 0; it < (SEQ - 4) / 4; ++it) {
        CRF_STEP(ring0, ring1, mr0, true, 0, 0)
        CRF_STEP(ring1, ring2, mr1, true, 1, 1)
        CRF_STEP(ring2, ring3, mr2, true, 2, 0)
        CRF_STEP(ring3, ring0, mr3, true, 3, 1)
        emp += 4 * NT;
        mpp += 4;
    }
    // tail: steps 1020..1023 (no prefetch; final ex compute is dead)
    CRF_STEP(ring0, ring1, mr0, false, 0, 0)
    CRF_STEP(ring1, ring2, mr1, false, 0, 1)
    CRF_STEP(ring2, ring3, mr2, false, 0, 0)
    CRF_STEP(ring3, ring3, mr3, false, 0, 1)

    // ---- log_z = offset + log( sum_j P_j * exp(end_j) ) ----
    float term = cur * __expf(end_t[c]);
    #pragma unroll
    for (int off = 32; off; off >>= 1)
        term += __shfl_xor(term, off);
    if (l == 0) redA[w] = term;

    // ---- gold-path score (128 threads, 8 s-iters each) ----
    const int tbase = b * SEQ;
    float sc = 0.0f, sm = 0.0f;
    for (int s = tid; s < SEQ; s += 128) {
        float m = msk_s[s];
        sm += m;
        if (s < SEQ - 1) {
            int tg  = tags[tbase + s];
            int tg1 = tags[tbase + s + 1];
            sc += eb[(size_t)s * NT + tg] * m;
            sc += transitions[tg * NT + tg1] * msk_s[s + 1];
        }
    }
    #pragma unroll
    for (int off = 32; off; off >>= 1) {
        sc += __shfl_xor(sc, off);
        sm += __shfl_xor(sm, off);
    }
    if (l == 0) { redB[w] = sc; redC[w] = sm; }
    __syncthreads();

    if (tid == 0) {
        float term_t = redA[0] + redA[1];
        float log_z  = offset + __logf(term_t);
        float sct    = redB[0] + redB[1];
        float smt    = redC[0] + redC[1];
        int tg0 = tags[tbase];
        int tgl = tags[tbase + SEQ - 1];
        sct += start_t[tg0];
        int last_ix = (int)fmaxf(smt - 1.0f, 0.0f);
        float ml = msk_s[SEQ - 1];
        sct += eb[(size_t)last_ix * NT + tgl] * ml;
        sct += end_t[tgl] * ml;
        out_per_batch[b] = log_z - sct;
    }
}

// mean over batch -> scalar output
__global__ void crf_reduce_kernel(const float* __restrict__ pb, float* __restrict__ out)
{
    float v = pb[threadIdx.x];   // 256 threads, one per batch
    #pragma unroll
    for (int off = 32; off; off >>= 1)
        v += __shfl_xor(v, off);
    __shared__ float s4[4];
    if ((threadIdx.x & 63) == 0) s4[threadIdx.x >> 6] = v;
    __syncthreads();
    if (threadIdx.x == 0)
        out[0] = (s4[0] + s4[1] + s4[2] + s4[3]) * (1.0f / 256.0f);
}

extern "C" void kernel_launch(void* const* d_in, const int* in_sizes, int n_in,
                              void* d_out, int out_size, void* d_ws, size_t ws_size,
                              hipStream_t stream) {
    const float* emissions   = (const float*)d_in[0];
    const float* masks       = (const float*)d_in[1];
    const int*   tags        = (const int*)  d_in[2];
    const float* transitions = (const float*)d_in[3];
    const float* start_t     = (const float*)d_in[4];
    const float* end_t       = (const float*)d_in[5];
    float* per_batch = (float*)d_ws;

    crf_scan_kernel<<<NB, 128, 0, stream>>>(emissions, masks, tags, transitions,
                                            start_t, end_t, per_batch);
    crf_reduce_kernel<<<1, 256, 0, stream>>>(per_batch, (float*)d_out);
}

// Round 7
// 563.339 us; speedup vs baseline: 1.7393x; 1.7393x over previous
//
#include <hip/hip_runtime.h>

#define NT 128      // num tags
#define SEQ 1024    // sequence length
#define NB 256      // batch

typedef _Float16 half2v __attribute__((ext_vector_type(2)));

// One DPP max step on the VALU pipe (no DS/lgkmcnt involvement).
#define DPP_MAX_STEP(x, ctrl)                                                   \
    fmaxf((x), __builtin_bit_cast(float, __builtin_amdgcn_update_dpp(           \
        __builtin_bit_cast(int, (x)), __builtin_bit_cast(int, (x)),             \
        (ctrl), 0xf, 0xf, false)))

__device__ __forceinline__ float wave_max_dpp(float x) {
    x = DPP_MAX_STEP(x, 0x111);   // row_shr:1
    x = DPP_MAX_STEP(x, 0x112);   // row_shr:2
    x = DPP_MAX_STEP(x, 0x114);   // row_shr:4
    x = DPP_MAX_STEP(x, 0x118);   // row_shr:8
    x = DPP_MAX_STEP(x, 0x142);   // row_bcast:15
    x = DPP_MAX_STEP(x, 0x143);   // row_bcast:31
    return __builtin_bit_cast(float, __builtin_amdgcn_readlane(
        __builtin_bit_cast(int, x), 63));
}

// lane[i] + lane[i^32] on the VALU pipe (v_permlane32_swap_b32, gfx950).
// With a=b=x, after the swap a+b == x[i&31] + x[(i&31)+32] in every lane.
__device__ __forceinline__ float cross32_add(float x) {
    float a = x, b = x;
    asm volatile("v_permlane32_swap_b32 %0, %1" : "+v"(a), "+v"(b));
    return a + b;
}

// lane[i^1] via DPP quad_perm [1,0,3,2] (ctrl 0xB1) -- VALU, exact.
__device__ __forceinline__ float swap1_dpp(float x) {
    return __builtin_bit_cast(float, __builtin_amdgcn_update_dpp(
        0, __builtin_bit_cast(int, x), 0xB1, 0xf, 0xf, true));
}

// LDS-only barrier: drain the DS pipe (our ds_write of P/wmax must be
// LDS-visible before other waves' post-barrier reads), then s_barrier --
// in ONE asm so no sched_barrier is needed and the compiler keeps its own
// scheduling freedom elsewhere. Critically this does NOT drain vmcnt: the
// depth-4 emission/mask ring prefetches stay in flight across the barrier
// (their use-site s_waitcnt vmcnt(N) lands ~3.5 steps after issue).
// __syncthreads() would emit s_waitcnt vmcnt(0) before s_barrier, exposing
// L3/HBM load latency (~400-900 cy) on every one of the 1024 steps.
__device__ __forceinline__ void barrier_lds() {
    asm volatile("s_waitcnt lgkmcnt(0)\n\ts_barrier" ::: "memory");
}

// One scan step, 4-wave cooperative version.
// Wave w owns columns [32w,32w+32); lane: col c=32w+(l&31), K-half ih=l>>5.
// P lives in LDS as packed f16 pairs (64 uints), double-buffered (BUF).
// One barrier per step: reads of buffer BUF precede the barrier, the next
// step's writes target BUF^1 only after it (ping-pong, no 2nd barrier).
// All shuffle traffic (K-half combine, pack-partner exchange, wave max) is
// VALU (permlane/DPP); DS pipe carries only the cross-wave P/wmax exchange.
#define CRF_STEP(RC, RN, MC, DO_PRE, K, BUF)                                     \
    {                                                                            \
        float mcur = MC;                                                         \
        if (DO_PRE) { RC = emp[(K) * NT]; MC = mpp[K]; }                         \
        float eRN = __expf(RN);          /* hoisted off the post-barrier path */ \
        const uint4* p4 = (const uint4*)&p_lds[BUF][ih * 32];                    \
        float A0=0.f, A1=0.f, A2=0.f, A3=0.f;                                    \
        _Pragma("unroll")                                                        \
        for (int qi = 0; qi < 8; ++qi) {                                         \
            uint4 q = p4[qi];                                                    \
            A0 = __builtin_amdgcn_fdot2(__builtin_bit_cast(half2v, q.x),         \
                                        E[4*qi+0], A0, false);                   \
            A1 = __builtin_amdgcn_fdot2(__builtin_bit_cast(half2v, q.y),         \
                                        E[4*qi+1], A1, false);                   \
            A2 = __builtin_amdgcn_fdot2(__builtin_bit_cast(half2v, q.z),         \
                                        E[4*qi+2], A2, false);                   \
            A3 = __builtin_amdgcn_fdot2(__builtin_bit_cast(half2v, q.w),         \
                                        E[4*qi+3], A3, false);                   \
        }                                                                        \
        float sv = cross32_add((A0 + A1) + (A2 + A3));                           \
        float v = sv * ex;                                                       \
        if (mcur > 0.0f) { cur = v; offset += offadd; }                          \
        float curo = swap1_dpp(cur);     /* partner column for f16 pack */       \
        if (ih == 0 && (cl & 1) == 0)                                            \
            p_lds[(BUF)^1][16*w + (cl >> 1)] = __builtin_bit_cast(unsigned int,  \
                __builtin_amdgcn_cvt_pkrtz(cur, curo));                          \
        float wm = wave_max_dpp(cur);                                            \
        if (l == 0) wmax[(BUF)^1][w] = wm;                                       \
        barrier_lds();                                                           \
        float4 wv = *(const float4*)&wmax[(BUF)^1][0];                           \
        mx = fmaxf(fmaxf(wv.x, wv.y), fmaxf(wv.z, wv.w));                        \
        inv = __builtin_amdgcn_rcpf(256.0f * mx);                                \
        offadd = __logf(mx) + 5.545177444479562f;                                \
        ex = eRN * inv;                                                          \
    }

// FOUR WAVES per batch element (one per SIMD of a CU). 256 blocks x 256
// threads. The 128x128 matvec is split 4 ways; P and the per-wave maxes are
// exchanged through double-buffered LDS with one LDS-only barrier per step
// (lgkmcnt drain only -- ring prefetch loads stay in flight across it).
__global__ __launch_bounds__(256, 1) void crf_scan_kernel(
    const float* __restrict__ emissions,    // [B,S,T]
    const float* __restrict__ masks,        // [B,S]
    const int*   __restrict__ tags,         // [B,S]
    const float* __restrict__ transitions,  // [T,T] (log domain)
    const float* __restrict__ start_t,      // [T]
    const float* __restrict__ end_t,        // [T]
    float* __restrict__ out_per_batch)      // [B]
{
    const int b   = blockIdx.x;
    const int tid = threadIdx.x;
    const int w   = tid >> 6;     // wave 0..3
    const int l   = tid & 63;     // lane 0..63
    const int cl  = l & 31;       // column within wave
    const int ih  = l >> 5;       // which half of the i (row) range
    const int c   = 32 * w + cl;  // owned output column
    const int i0  = 64 * ih;      // start of this lane's i range

    __shared__ __align__(16) unsigned int p_lds[2][64]; // packed f16 P pairs
    __shared__ __align__(16) float        wmax[2][4];   // per-wave maxes
    __shared__ float redA[4], redB[4], redC[4];         // epilogue reductions
    __shared__ float msk_s[SEQ];

    // ---- E fragment: rows i0+2r, i0+2r+1 of column c, prob domain f16 ----
    half2v E[32];
    #pragma unroll
    for (int r = 0; r < 32; ++r) {
        float ea = transitions[(i0 + 2*r    ) * NT + c];
        float ob = transitions[(i0 + 2*r + 1) * NT + c];
        E[r] = half2v{(_Float16)__expf(ea), (_Float16)__expf(ob)};
    }

    for (int s = tid; s < SEQ; s += 256)
        msk_s[s] = masks[b * SEQ + s];

    // ---- init: P = exp(start), offset = 0 ----
    float cur = __expf(start_t[c]);
    float offset = 0.0f;

    {
        float curo = swap1_dpp(cur);
        if (ih == 0 && (cl & 1) == 0)
            p_lds[0][16*w + (cl >> 1)] = __builtin_bit_cast(unsigned int,
                __builtin_amdgcn_cvt_pkrtz(cur, curo));
        float wm = wave_max_dpp(cur);
        if (l == 0) wmax[0][w] = wm;
    }
    __syncthreads();

    float4 wv0 = *(const float4*)&wmax[0][0];
    float mx   = fmaxf(fmaxf(wv0.x, wv0.y), fmaxf(wv0.z, wv0.w));
    float inv  = __builtin_amdgcn_rcpf(256.0f * mx);
    float offadd = __logf(mx) + 5.545177444479562f;   // log(256*mx)

    const float* eb  = emissions + (size_t)b * SEQ * NT;
    const float* mkp = masks + b * SEQ;

    // depth-4 rings: slot k holds em/mask for step s with s&3==k (scalar)
    float ring0 = eb[(size_t)0 * NT + c];
    float ring1 = eb[(size_t)1 * NT + c];
    float ring2 = eb[(size_t)2 * NT + c];
    float ring3 = eb[(size_t)3 * NT + c];
    float mr0 = mkp[0], mr1 = mkp[1], mr2 = mkp[2], mr3 = mkp[3];

    float ex = __expf(ring0) * inv;

    const float* emp = eb + 4 * NT + c;   // em[s+4] for s=0
    const float* mpp = mkp + 4;

    // main loop: steps 0..1019, unrolled x4 (ring slots static; BUF = s&1)
    for (int it = 0; it < (SEQ - 4) / 4; ++it) {
        CRF_STEP(ring0, ring1, mr0, true, 0, 0)
        CRF_STEP(ring1, ring2, mr1, true, 1, 1)
        CRF_STEP(ring2, ring3, mr2, true, 2, 0)
        CRF_STEP(ring3, ring0, mr3, true, 3, 1)
        emp += 4 * NT;
        mpp += 4;
    }
    // tail: steps 1020..1023 (no prefetch)
    CRF_STEP(ring0, ring1, mr0, false, 0, 0)
    CRF_STEP(ring1, ring2, mr1, false, 0, 1)
    CRF_STEP(ring2, ring3, mr2, false, 0, 0)
    CRF_STEP(ring3, ring3, mr3, false, 0, 1)

    // ---- log_z = offset + log( sum_j P_j * exp(end_j) ) ----
    float term = (ih == 0) ? cur * __expf(end_t[c]) : 0.0f;
    #pragma unroll
    for (int off = 32; off; off >>= 1)
        term += __shfl_xor(term, off);
    if (l == 0) redA[w] = term;

    // ---- gold-path score (256 threads, 4 s-iters each) ----
    const int tbase = b * SEQ;
    float sc = 0.0f, sm = 0.0f;
    for (int s = tid; s < SEQ; s += 256) {
        float m = msk_s[s];
        sm += m;
        if (s < SEQ - 1) {
            int tg  = tags[tbase + s];
            int tg1 = tags[tbase + s + 1];
            sc += eb[(size_t)s * NT + tg] * m;
            sc += transitions[tg * NT + tg1] * msk_s[s + 1];
        }
    }
    #pragma unroll
    for (int off = 32; off; off >>= 1) {
        sc += __shfl_xor(sc, off);
        sm += __shfl_xor(sm, off);
    }
    if (l == 0) { redB[w] = sc; redC[w] = sm; }
    __syncthreads();

    if (tid == 0) {
        float term_t = (redA[0] + redA[1]) + (redA[2] + redA[3]);
        float log_z  = offset + __logf(term_t);
        float sct    = (redB[0] + redB[1]) + (redB[2] + redB[3]);
        float smt    = (redC[0] + redC[1]) + (redC[2] + redC[3]);
        int tg0 = tags[tbase];
        int tgl = tags[tbase + SEQ - 1];
        sct += start_t[tg0];
        int last_ix = (int)fmaxf(smt - 1.0f, 0.0f);
        float ml = msk_s[SEQ - 1];
        sct += eb[(size_t)last_ix * NT + tgl] * ml;
        sct += end_t[tgl] * ml;
        out_per_batch[b] = log_z - sct;
    }
}

// mean over batch -> scalar output
__global__ void crf_reduce_kernel(const float* __restrict__ pb, float* __restrict__ out)
{
    float v = pb[threadIdx.x];   // 256 threads, one per batch
    #pragma unroll
    for (int off = 32; off; off >>= 1)
        v += __shfl_xor(v, off);
    __shared__ float s4[4];
    if ((threadIdx.x & 63) == 0) s4[threadIdx.x >> 6] = v;
    __syncthreads();
    if (threadIdx.x == 0)
        out[0] = (s4[0] + s4[1] + s4[2] + s4[3]) * (1.0f / 256.0f);
}

extern "C" void kernel_launch(void* const* d_in, const int* in_sizes, int n_in,
                              void* d_out, int out_size, void* d_ws, size_t ws_size,
                              hipStream_t stream) {
    const float* emissions   = (const float*)d_in[0];
    const float* masks       = (const float*)d_in[1];
    const int*   tags        = (const int*)  d_in[2];
    const float* transitions = (const float*)d_in[3];
    const float* start_t     = (const float*)d_in[4];
    const float* end_t       = (const float*)d_in[5];
    float* per_batch = (float*)d_ws;

    crf_scan_kernel<<<NB, 256, 0, stream>>>(emissions, masks, tags, transitions,
                                            start_t, end_t, per_batch);
    crf_reduce_kernel<<<1, 256, 0, stream>>>(per_batch, (float*)d_out);
}